// Round 2
// baseline (2455.649 us; speedup 1.0000x reference)
//
#include <hip/hip_runtime.h>
#include <stdint.h>

typedef float f32x4 __attribute__((ext_vector_type(4)));
typedef short s16x8 __attribute__((ext_vector_type(8)));
typedef short s16x4 __attribute__((ext_vector_type(4)));

#define HDIM 128
#define TLEN 512
#define BT 16

__device__ __forceinline__ unsigned short f2bf(float f) {
    union { float f; uint32_t u; } v; v.f = f;
    uint32_t r = v.u + 0x7FFFu + ((v.u >> 16) & 1u);
    return (unsigned short)(r >> 16);
}
__device__ __forceinline__ float bfhi(uint32_t u){ union{uint32_t u;float f;}v; v.u = u & 0xFFFF0000u; return v.f; }
__device__ __forceinline__ float bflo(uint32_t u){ union{uint32_t u;float f;}v; v.u = u << 16; return v.f; }
__device__ __forceinline__ float bf2f(short s){ union{uint32_t u;float f;}v; v.u = ((uint32_t)(unsigned short)s) << 16; return v.f; }

__device__ __forceinline__ float sigmoidf_(float x){
    float e = __expf(-x);
    return __builtin_amdgcn_rcpf(1.0f + e);
}
__device__ __forceinline__ float tanhf_(float x){
    float e = __expf(2.0f * x);
    return 1.0f - 2.0f * __builtin_amdgcn_rcpf(1.0f + e);
}

__global__ __launch_bounds__(512, 2) void lstm_fused_kernel(
    const float* __restrict__ x,      // (2048,512,1)
    const float* __restrict__ Wih0,   // (512,1)
    const float* __restrict__ Whh0,   // (512,128)
    const float* __restrict__ bih0,
    const float* __restrict__ bhh0,
    const float* __restrict__ Wih1,   // (512,128)
    const float* __restrict__ Whh1,   // (512,128)
    const float* __restrict__ bih1,
    const float* __restrict__ bhh1,
    const float* __restrict__ W1,     // (64,128)
    const float* __restrict__ b1,     // (64)
    const float* __restrict__ W2,     // (8,64)
    const float* __restrict__ b2,     // (8)
    float* __restrict__ out)          // (2048,8)
{
    // Double-buffered h fragments (B-operand order), x tile, head scratch.
    __shared__ __align__(16) short h0f0[2048], h0f1[2048];
    __shared__ __align__(16) short h1f0[2048], h1f1[2048];
    __shared__ __align__(16) float xlds[64 * 16];       // [t&63][n]
    __shared__ __align__(16) float headH[16 * HDIM];    // final h1, f32
    __shared__ __align__(16) float headL[16 * 64];      // relu layer

    const int tid = threadIdx.x;
    const int w = tid >> 6;     // wave 0..7 ; owns units [16w,16w+16)
    const int l = tid & 63;
    const int n = l & 15;       // batch col (B) / row-in-tile (A)
    const int q = l >> 4;       // k-group
    const int b0 = blockIdx.x * BT;

    // ---- ALL recurrent weights in registers (bf16 fragments) ----
    s16x8 w0f[4][4], wi1f[4][4], wh1f[4][4];
    #pragma unroll
    for (int c = 0; c < 4; ++c) {
        #pragma unroll
        for (int tile = 0; tile < 4; ++tile) {
            const int g  = tile * 128 + w * 16 + n;   // gate row
            const int k0 = c * 32 + q * 8;
            const float* p0 = Whh0 + g * HDIM + k0;
            const float* p1 = Wih1 + g * HDIM + k0;
            const float* p2 = Whh1 + g * HDIM + k0;
            s16x8 a0, a1, a2;
            #pragma unroll
            for (int j = 0; j < 8; ++j) {
                a0[j] = (short)f2bf(p0[j]);
                a1[j] = (short)f2bf(p1[j]);
                a2[j] = (short)f2bf(p2[j]);
            }
            w0f[c][tile] = a0; wi1f[c][tile] = a1; wh1f[c][tile] = a2;
        }
    }

    // ---- per-lane constants: packed-bf16 biases + x-weight ----
    const int u0 = w * 16 + q * 4;          // first of this lane's 4 units
    uint32_t b0p[8], b1p[8], wxp[8];
    #pragma unroll
    for (int i = 0; i < 8; ++i) {
        const int tr0 = 2 * i;
        const int tile = tr0 >> 2, r0 = tr0 & 3;
        const int g0 = tile * 128 + u0 + r0;
        const int g1 = g0 + 1;
        b0p[i] = ((uint32_t)f2bf(bih0[g1] + bhh0[g1]) << 16) | f2bf(bih0[g0] + bhh0[g0]);
        b1p[i] = ((uint32_t)f2bf(bih1[g1] + bhh1[g1]) << 16) | f2bf(bih1[g0] + bhh1[g0]);
        wxp[i] = ((uint32_t)f2bf(Wih0[g1]) << 16) | f2bf(Wih0[g0]);
    }

    // zero the t=0 read buffers (h_{-1} = 0)
    for (int s2 = tid; s2 < 1024; s2 += 512) {
        ((uint32_t*)h0f1)[s2] = 0u;
        ((uint32_t*)h1f1)[s2] = 0u;
    }

    // B-fragment write slot for this lane's 4 units
    const int cp  = u0 >> 5;
    const int kbp = (u0 >> 3) & 3;
    const int j0  = u0 & 7;
    const int fragoff = (cp * 64 + (n + 16 * kbp)) * 8 + j0;   // short index

    float c0v[4] = {0.f, 0.f, 0.f, 0.f};
    float c1v[4] = {0.f, 0.f, 0.f, 0.f};

#define REFILL(T) do {                                                        \
    _Pragma("unroll")                                                         \
    for (int i2 = 0; i2 < 2; ++i2) {                                          \
        const int idx = tid + i2 * 512;                                       \
        const int tt = idx & 63, nn = idx >> 6;                               \
        xlds[tt * 16 + nn] = x[(size_t)(b0 + nn) * TLEN + (T) + tt];          \
    }                                                                         \
    __syncthreads();                                                          \
  } while (0)

#define STEP(T, H0R, H0W, H1R, H1W) do {                                      \
    const float xv_ = xlds[((T) & 63) * 16 + n];                              \
    f32x4 acc_[4];                                                            \
    _Pragma("unroll")                                                         \
    for (int tile = 0; tile < 4; ++tile) {                                    \
        _Pragma("unroll")                                                     \
        for (int r = 0; r < 4; ++r) {                                         \
            const int tr = tile * 4 + r;                                      \
            const float bb = (tr & 1) ? bfhi(b0p[tr >> 1]) : bflo(b0p[tr >> 1]); \
            const float wv = (tr & 1) ? bfhi(wxp[tr >> 1]) : bflo(wxp[tr >> 1]); \
            acc_[tile][r] = fmaf(wv, xv_, bb);                                \
        }                                                                     \
    }                                                                         \
    _Pragma("unroll")                                                         \
    for (int c = 0; c < 4; ++c) {                                             \
        const s16x8 hb = *(const s16x8*)&(H0R)[(c * 64 + l) * 8];             \
        _Pragma("unroll")                                                     \
        for (int tile = 0; tile < 4; ++tile)                                  \
            acc_[tile] = __builtin_amdgcn_mfma_f32_16x16x32_bf16(w0f[c][tile], hb, acc_[tile], 0, 0, 0); \
    }                                                                         \
    {                                                                         \
        s16x4 hw;                                                             \
        _Pragma("unroll")                                                     \
        for (int r = 0; r < 4; ++r) {                                         \
            const float ig = sigmoidf_(acc_[0][r]);                           \
            const float fg = sigmoidf_(acc_[1][r]);                           \
            const float gg = tanhf_(acc_[2][r]);                              \
            const float og = sigmoidf_(acc_[3][r]);                           \
            const float cc = fmaf(fg, c0v[r], ig * gg);                       \
            c0v[r] = cc;                                                      \
            hw[r] = (short)f2bf(og * tanhf_(cc));                             \
        }                                                                     \
        *(s16x4*)&(H0W)[fragoff] = hw;                                        \
    }                                                                         \
    __syncthreads();                                                          \
    _Pragma("unroll")                                                         \
    for (int tile = 0; tile < 4; ++tile) {                                    \
        _Pragma("unroll")                                                     \
        for (int r = 0; r < 4; ++r) {                                         \
            const int tr = tile * 4 + r;                                      \
            acc_[tile][r] = (tr & 1) ? bfhi(b1p[tr >> 1]) : bflo(b1p[tr >> 1]); \
        }                                                                     \
    }                                                                         \
    _Pragma("unroll")                                                         \
    for (int c = 0; c < 4; ++c) {                                             \
        const s16x8 hb0 = *(const s16x8*)&(H0W)[(c * 64 + l) * 8];            \
        const s16x8 hb1 = *(const s16x8*)&(H1R)[(c * 64 + l) * 8];            \
        _Pragma("unroll")                                                     \
        for (int tile = 0; tile < 4; ++tile) {                                \
            acc_[tile] = __builtin_amdgcn_mfma_f32_16x16x32_bf16(wi1f[c][tile], hb0, acc_[tile], 0, 0, 0); \
            acc_[tile] = __builtin_amdgcn_mfma_f32_16x16x32_bf16(wh1f[c][tile], hb1, acc_[tile], 0, 0, 0); \
        }                                                                     \
    }                                                                         \
    {                                                                         \
        s16x4 hw;                                                             \
        _Pragma("unroll")                                                     \
        for (int r = 0; r < 4; ++r) {                                         \
            const float ig = sigmoidf_(acc_[0][r]);                           \
            const float fg = sigmoidf_(acc_[1][r]);                           \
            const float gg = tanhf_(acc_[2][r]);                              \
            const float og = sigmoidf_(acc_[3][r]);                           \
            const float cc = fmaf(fg, c1v[r], ig * gg);                       \
            c1v[r] = cc;                                                      \
            hw[r] = (short)f2bf(og * tanhf_(cc));                             \
        }                                                                     \
        *(s16x4*)&(H1W)[fragoff] = hw;                                        \
    }                                                                         \
  } while (0)

    #pragma unroll 1
    for (int t = 0; t < TLEN; t += 2) {
        if ((t & 63) == 0) REFILL(t);
        STEP(t,     h0f1, h0f0, h1f1, h1f0);
        STEP(t + 1, h0f0, h0f1, h1f0, h1f1);
    }

    // ---- head ----
    {   // final h1 (t=511, odd) lives in h1f1; each lane re-reads its own slot
        const s16x4 hv = *(const s16x4*)&h1f1[fragoff];
        f32x4 hf;
        #pragma unroll
        for (int r = 0; r < 4; ++r) hf[r] = bf2f(hv[r]);
        *(f32x4*)&headH[n * HDIM + u0] = hf;
    }
    __syncthreads();

    #pragma unroll
    for (int rep = 0; rep < 2; ++rep) {
        const int idx = tid + rep * 512;     // 1024 = 16 batch * 64 hidden
        const int nn = idx >> 6, j = idx & 63;
        float s = b1[j];
        const float* wrow = W1 + j * HDIM;
        const float* hrow = headH + nn * HDIM;
        #pragma unroll
        for (int k = 0; k < HDIM; k += 4) {
            const f32x4 hv = *(const f32x4*)&hrow[k];
            const f32x4 wv = *(const f32x4*)&wrow[k];
            s += hv[0]*wv[0] + hv[1]*wv[1] + hv[2]*wv[2] + hv[3]*wv[3];
        }
        headL[nn * 64 + j] = fmaxf(s, 0.0f);
    }
    __syncthreads();

    if (tid < 128) {
        const int nn = tid >> 3, cls = tid & 7;
        float s = b2[cls];
        const float* wrow = W2 + cls * 64;
        const float* hrow = headL + nn * 64;
        #pragma unroll
        for (int k = 0; k < 64; k += 4) {
            const f32x4 hv = *(const f32x4*)&hrow[k];
            const f32x4 wv = *(const f32x4*)&wrow[k];
            s += hv[0]*wv[0] + hv[1]*wv[1] + hv[2]*wv[2] + hv[3]*wv[3];
        }
        out[(size_t)(b0 + nn) * 8 + cls] = s;
    }
}

extern "C" void kernel_launch(void* const* d_in, const int* in_sizes, int n_in,
                              void* d_out, int out_size, void* d_ws, size_t ws_size,
                              hipStream_t stream) {
    const float* x    = (const float*)d_in[0];
    const float* Wih0 = (const float*)d_in[1];
    const float* Whh0 = (const float*)d_in[2];
    const float* bih0 = (const float*)d_in[3];
    const float* bhh0 = (const float*)d_in[4];
    const float* Wih1 = (const float*)d_in[5];
    const float* Whh1 = (const float*)d_in[6];
    const float* bih1 = (const float*)d_in[7];
    const float* bhh1 = (const float*)d_in[8];
    const float* W1   = (const float*)d_in[9];
    const float* b1   = (const float*)d_in[10];
    const float* W2   = (const float*)d_in[11];
    const float* b2   = (const float*)d_in[12];
    float* outp = (float*)d_out;

    lstm_fused_kernel<<<128, 512, 0, stream>>>(
        x, Wih0, Whh0, bih0, bhh0, Wih1, Whh1, bih1, bhh1, W1, b1, W2, b2, outp);
}

// Round 3
// 1039.137 us; speedup vs baseline: 2.3632x; 2.3632x over previous
//
#include <hip/hip_runtime.h>
#include <stdint.h>

typedef float f32x4 __attribute__((ext_vector_type(4)));
typedef short s16x8 __attribute__((ext_vector_type(8)));
typedef short s16x4 __attribute__((ext_vector_type(4)));

#define HDIM 128
#define TLEN 512
#define BT 16

__device__ __forceinline__ unsigned short f2bf(float f) {
    union { float f; uint32_t u; } v; v.f = f;
    uint32_t r = v.u + 0x7FFFu + ((v.u >> 16) & 1u);
    return (unsigned short)(r >> 16);
}
__device__ __forceinline__ float bfhi(uint32_t u){ union{uint32_t u;float f;}v; v.u = u & 0xFFFF0000u; return v.f; }
__device__ __forceinline__ float bflo(uint32_t u){ union{uint32_t u;float f;}v; v.u = u << 16; return v.f; }
__device__ __forceinline__ float bf2f(short s){ union{uint32_t u;float f;}v; v.u = ((uint32_t)(unsigned short)s) << 16; return v.f; }

__device__ __forceinline__ float sigmoidf_(float x){
    float e = __expf(-x);
    return __builtin_amdgcn_rcpf(1.0f + e);
}
__device__ __forceinline__ float tanhf_(float x){
    float e = __expf(2.0f * x);
    return 1.0f - 2.0f * __builtin_amdgcn_rcpf(1.0f + e);
}

__global__ __launch_bounds__(512, 2) void lstm_fused_kernel(
    const float* __restrict__ x,      // (2048,512,1)
    const float* __restrict__ Wih0,   // (512,1)
    const float* __restrict__ Whh0,   // (512,128)
    const float* __restrict__ bih0,
    const float* __restrict__ bhh0,
    const float* __restrict__ Wih1,   // (512,128)
    const float* __restrict__ Whh1,   // (512,128)
    const float* __restrict__ bih1,
    const float* __restrict__ bhh1,
    const float* __restrict__ W1,     // (64,128)
    const float* __restrict__ b1,     // (64)
    const float* __restrict__ W2,     // (8,64)
    const float* __restrict__ b2,     // (8)
    float* __restrict__ out)          // (2048,8)
{
    // W_hh0 fragment-ordered in LDS (128KB); ping-pong h fragments; x tile.
    __shared__ __align__(16) short w0lds[65536];   // [c][w][tile][lane] * 8 shorts
    __shared__ __align__(16) short h0f0[2048], h0f1[2048];
    __shared__ __align__(16) short h1f0[2048], h1f1[2048];
    __shared__ __align__(16) float xlds[64 * 16];  // [t&63][n]

    const int tid = threadIdx.x;
    const int w = tid >> 6;     // wave 0..7 ; owns units [16w,16w+16)
    const int l = tid & 63;
    const int n = l & 15;       // batch col (B) / row-in-tile (A)
    const int q = l >> 4;       // k-group
    const int b0 = blockIdx.x * BT;

    // ---- W_ih1 / W_hh1 fragments in registers (bf16) ----
    s16x8 wi1f[4][4], wh1f[4][4];
    #pragma unroll
    for (int c = 0; c < 4; ++c) {
        #pragma unroll
        for (int tile = 0; tile < 4; ++tile) {
            const int g  = tile * 128 + w * 16 + n;   // gate row
            const int k0 = c * 32 + q * 8;
            const float* p1 = Wih1 + g * HDIM + k0;
            const float* p2 = Whh1 + g * HDIM + k0;
            s16x8 a, b;
            #pragma unroll
            for (int j = 0; j < 8; ++j) { a[j] = (short)f2bf(p1[j]); b[j] = (short)f2bf(p2[j]); }
            wi1f[c][tile] = a; wh1f[c][tile] = b;
        }
    }

    // ---- W_hh0 into LDS, fragment-ordered ----
    for (int s2 = tid; s2 < 8192; s2 += 512) {
        const int ll = s2 & 63, tl = (s2 >> 6) & 3, ww = (s2 >> 8) & 7, cc = s2 >> 11;
        const int g  = tl * 128 + ww * 16 + (ll & 15);
        const int k0 = cc * 32 + (ll >> 4) * 8;
        const float* p = Whh0 + g * HDIM + k0;
        s16x8 a;
        #pragma unroll
        for (int j = 0; j < 8; ++j) a[j] = (short)f2bf(p[j]);
        *(s16x8*)&w0lds[s2 * 8] = a;
    }

    // ---- per-lane constants: packed-bf16 biases + x-weight ----
    const int u0 = w * 16 + q * 4;          // first of this lane's 4 units
    uint32_t b0p[8], b1p[8], wxp[8];
    #pragma unroll
    for (int i = 0; i < 8; ++i) {
        const int tr0 = 2 * i;
        const int tile = tr0 >> 2, r0 = tr0 & 3;
        const int g0 = tile * 128 + u0 + r0;
        const int g1 = g0 + 1;
        b0p[i] = ((uint32_t)f2bf(bih0[g1] + bhh0[g1]) << 16) | f2bf(bih0[g0] + bhh0[g0]);
        b1p[i] = ((uint32_t)f2bf(bih1[g1] + bhh1[g1]) << 16) | f2bf(bih1[g0] + bhh1[g0]);
        wxp[i] = ((uint32_t)f2bf(Wih0[g1]) << 16) | f2bf(Wih0[g0]);
    }

    // zero the t=0 read buffers
    for (int s2 = tid; s2 < 1024; s2 += 512) {
        ((uint32_t*)h0f1)[s2] = 0u;
        ((uint32_t*)h1f1)[s2] = 0u;
    }

    // B-fragment write slot for this lane's 4 units
    const int cp  = u0 >> 5;
    const int kbp = (u0 >> 3) & 3;
    const int j0  = u0 & 7;
    const int fragoff = (cp * 64 + (n + 16 * kbp)) * 8 + j0;   // short index

    float c0v[4] = {0.f, 0.f, 0.f, 0.f};
    float c1v[4] = {0.f, 0.f, 0.f, 0.f};

    // cached h0 B-fragments (h0[t-1]); init to 0 for t=0
    s16x8 hbc[4];
    #pragma unroll
    for (int c = 0; c < 4; ++c) {
        #pragma unroll
        for (int j = 0; j < 8; ++j) hbc[c][j] = 0;
    }

#define REFILL(T) do {                                                        \
    _Pragma("unroll")                                                         \
    for (int i2 = 0; i2 < 2; ++i2) {                                          \
        const int idx = tid + i2 * 512;                                       \
        const int tt = idx & 63, nn = idx >> 6;                               \
        xlds[tt * 16 + nn] = x[(size_t)(b0 + nn) * TLEN + (T) + tt];          \
    }                                                                         \
    __syncthreads();                                                          \
  } while (0)

#define STEP(T, H0W, H1R, H1W) do {                                          \
    /* phase 1: gates0 = bias0 + Wih0*x + Whh0 @ h0[t-1] (B from hbc regs) */ \
    const float xv_ = xlds[((T) & 63) * 16 + n];                              \
    f32x4 acc_[4];                                                            \
    _Pragma("unroll")                                                         \
    for (int tile = 0; tile < 4; ++tile) {                                    \
        _Pragma("unroll")                                                     \
        for (int r = 0; r < 4; ++r) {                                         \
            const int tr = tile * 4 + r;                                      \
            const float bb = (tr & 1) ? bfhi(b0p[tr >> 1]) : bflo(b0p[tr >> 1]); \
            const float wv = (tr & 1) ? bfhi(wxp[tr >> 1]) : bflo(wxp[tr >> 1]); \
            acc_[tile][r] = fmaf(wv, xv_, bb);                                \
        }                                                                     \
    }                                                                         \
    _Pragma("unroll")                                                         \
    for (int c = 0; c < 4; ++c) {                                             \
        _Pragma("unroll")                                                     \
        for (int tile = 0; tile < 4; ++tile) {                                \
            const s16x8 a = *(const s16x8*)&w0lds[(((c * 8 + w) * 4 + tile) * 64 + l) * 8]; \
            acc_[tile] = __builtin_amdgcn_mfma_f32_16x16x32_bf16(a, hbc[c], acc_[tile], 0, 0, 0); \
        }                                                                     \
    }                                                                         \
    /* phase 2: layer-0 pointwise, write h0 fragment */                       \
    {                                                                         \
        s16x4 hw;                                                             \
        _Pragma("unroll")                                                     \
        for (int r = 0; r < 4; ++r) {                                         \
            const float ig = sigmoidf_(acc_[0][r]);                           \
            const float fg = sigmoidf_(acc_[1][r]);                           \
            const float gg = tanhf_(acc_[2][r]);                              \
            const float og = sigmoidf_(acc_[3][r]);                           \
            const float cc = fmaf(fg, c0v[r], ig * gg);                       \
            c0v[r] = cc;                                                      \
            hw[r] = (short)f2bf(og * tanhf_(cc));                             \
        }                                                                     \
        *(s16x4*)&(H0W)[fragoff] = hw;                                        \
    }                                                                         \
    __syncthreads();                                                          \
    /* phase 3: gates1 = bias1 + Wih1 @ h0[t] + Whh1 @ h1[t-1] */             \
    s16x8 hb1_[4];                                                            \
    _Pragma("unroll")                                                         \
    for (int c = 0; c < 4; ++c) {                                             \
        hbc[c]  = *(const s16x8*)&(H0W)[(c * 64 + l) * 8];                    \
        hb1_[c] = *(const s16x8*)&(H1R)[(c * 64 + l) * 8];                    \
    }                                                                         \
    _Pragma("unroll")                                                         \
    for (int tile = 0; tile < 4; ++tile) {                                    \
        _Pragma("unroll")                                                     \
        for (int r = 0; r < 4; ++r) {                                         \
            const int tr = tile * 4 + r;                                      \
            acc_[tile][r] = (tr & 1) ? bfhi(b1p[tr >> 1]) : bflo(b1p[tr >> 1]); \
        }                                                                     \
    }                                                                         \
    _Pragma("unroll")                                                         \
    for (int c = 0; c < 4; ++c) {                                             \
        _Pragma("unroll")                                                     \
        for (int tile = 0; tile < 4; ++tile) {                                \
            acc_[tile] = __builtin_amdgcn_mfma_f32_16x16x32_bf16(wi1f[c][tile], hbc[c], acc_[tile], 0, 0, 0); \
            acc_[tile] = __builtin_amdgcn_mfma_f32_16x16x32_bf16(wh1f[c][tile], hb1_[c], acc_[tile], 0, 0, 0); \
        }                                                                     \
    }                                                                         \
    /* phase 4: layer-1 pointwise, write h1 fragment */                       \
    {                                                                         \
        s16x4 hw;                                                             \
        _Pragma("unroll")                                                     \
        for (int r = 0; r < 4; ++r) {                                         \
            const float ig = sigmoidf_(acc_[0][r]);                           \
            const float fg = sigmoidf_(acc_[1][r]);                           \
            const float gg = tanhf_(acc_[2][r]);                              \
            const float og = sigmoidf_(acc_[3][r]);                           \
            const float cc = fmaf(fg, c1v[r], ig * gg);                       \
            c1v[r] = cc;                                                      \
            hw[r] = (short)f2bf(og * tanhf_(cc));                             \
        }                                                                     \
        *(s16x4*)&(H1W)[fragoff] = hw;                                        \
    }                                                                         \
  } while (0)

    __syncthreads();   // w0lds + zeroed buffers ready

    #pragma unroll 1
    for (int t = 0; t < TLEN; t += 2) {
        if ((t & 63) == 0) REFILL(t);
        STEP(t,     h0f0, h1f1, h1f0);
        STEP(t + 1, h0f1, h1f0, h1f1);
    }

    // ---- head: final h1 (t=511) is in h1f1; each lane re-reads its own slot ----
    float* headH = (float*)w0lds;            // [16][128] f32 scratch
    float* headL = ((float*)w0lds) + 2048;   // [16][64]
    {
        const s16x4 hv = *(const s16x4*)&h1f1[fragoff];
        f32x4 hf;
        #pragma unroll
        for (int r = 0; r < 4; ++r) hf[r] = bf2f(hv[r]);
        __syncthreads();                     // all waves done with w0lds reads
        *(f32x4*)&headH[n * HDIM + u0] = hf;
    }
    __syncthreads();

    #pragma unroll
    for (int rep = 0; rep < 2; ++rep) {
        const int idx = tid + rep * 512;     // 1024 = 16 batch * 64 hidden
        const int nn = idx >> 6, j = idx & 63;
        float s = b1[j];
        const float* wrow = W1 + j * HDIM;
        const float* hrow = headH + nn * HDIM;
        #pragma unroll
        for (int k = 0; k < HDIM; k += 4) {
            const f32x4 hv = *(const f32x4*)&hrow[k];
            const f32x4 wv = *(const f32x4*)&wrow[k];
            s += hv[0]*wv[0] + hv[1]*wv[1] + hv[2]*wv[2] + hv[3]*wv[3];
        }
        headL[nn * 64 + j] = fmaxf(s, 0.0f);
    }
    __syncthreads();

    if (tid < 128) {
        const int nn = tid >> 3, cls = tid & 7;
        float s = b2[cls];
        const float* wrow = W2 + cls * 64;
        const float* hrow = headL + nn * 64;
        #pragma unroll
        for (int k = 0; k < 64; k += 4) {
            const f32x4 hv = *(const f32x4*)&hrow[k];
            const f32x4 wv = *(const f32x4*)&wrow[k];
            s += hv[0]*wv[0] + hv[1]*wv[1] + hv[2]*wv[2] + hv[3]*wv[3];
        }
        out[(size_t)(b0 + nn) * 8 + cls] = s;
    }
}

extern "C" void kernel_launch(void* const* d_in, const int* in_sizes, int n_in,
                              void* d_out, int out_size, void* d_ws, size_t ws_size,
                              hipStream_t stream) {
    const float* x    = (const float*)d_in[0];
    const float* Wih0 = (const float*)d_in[1];
    const float* Whh0 = (const float*)d_in[2];
    const float* bih0 = (const float*)d_in[3];
    const float* bhh0 = (const float*)d_in[4];
    const float* Wih1 = (const float*)d_in[5];
    const float* Whh1 = (const float*)d_in[6];
    const float* bih1 = (const float*)d_in[7];
    const float* bhh1 = (const float*)d_in[8];
    const float* W1   = (const float*)d_in[9];
    const float* b1   = (const float*)d_in[10];
    const float* W2   = (const float*)d_in[11];
    const float* b2   = (const float*)d_in[12];
    float* outp = (float*)d_out;

    lstm_fused_kernel<<<128, 512, 0, stream>>>(
        x, Wih0, Whh0, bih0, bhh0, Wih1, Whh1, bih1, bhh1, W1, b1, W2, b2, outp);
}

// Round 4
// 1007.216 us; speedup vs baseline: 2.4381x; 1.0317x over previous
//
#include <hip/hip_runtime.h>
#include <stdint.h>

typedef float f32x4 __attribute__((ext_vector_type(4)));
typedef short s16x8 __attribute__((ext_vector_type(8)));
typedef short s16x4 __attribute__((ext_vector_type(4)));

#define HDIM 128
#define TLEN 512
#define BT 16

__device__ __forceinline__ unsigned short f2bf(float f) {
    union { float f; uint32_t u; } v; v.f = f;
    uint32_t r = v.u + 0x7FFFu + ((v.u >> 16) & 1u);
    return (unsigned short)(r >> 16);
}
__device__ __forceinline__ float bfhi(uint32_t u){ union{uint32_t u;float f;}v; v.u = u & 0xFFFF0000u; return v.f; }
__device__ __forceinline__ float bflo(uint32_t u){ union{uint32_t u;float f;}v; v.u = u << 16; return v.f; }

__device__ __forceinline__ float sigmoidf_(float x){
    float e = __expf(-x);
    return __builtin_amdgcn_rcpf(1.0f + e);
}
__device__ __forceinline__ float tanhf_(float x){
    float e = __expf(2.0f * x);
    return 1.0f - 2.0f * __builtin_amdgcn_rcpf(1.0f + e);
}

#define UNPK(arr, idx) (((idx) & 1) ? bfhi(arr[(idx) >> 1]) : bflo(arr[(idx) >> 1]))

__global__ __launch_bounds__(512, 2) void lstm_fused_kernel(
    const float* __restrict__ x,      // (2048,512,1)
    const float* __restrict__ Wih0,   // (512,1)
    const float* __restrict__ Whh0,   // (512,128)
    const float* __restrict__ bih0,
    const float* __restrict__ bhh0,
    const float* __restrict__ Wih1,   // (512,128)
    const float* __restrict__ Whh1,   // (512,128)
    const float* __restrict__ bih1,
    const float* __restrict__ bhh1,
    const float* __restrict__ W1,     // (64,128)
    const float* __restrict__ b1,     // (64)
    const float* __restrict__ W2,     // (8,64)
    const float* __restrict__ b2,     // (8)
    float* __restrict__ out)          // (2048,8)
{
    // W_hh0 fragment-ordered in LDS (128KB); ping-pong h fragments.
    __shared__ __align__(16) short w0lds[65536];   // [c][w][tile][lane] * 8 shorts
    __shared__ __align__(16) short h0f0[2048], h0f1[2048];
    __shared__ __align__(16) short h1f0[2048], h1f1[2048];

    const int tid = threadIdx.x;
    const int w = tid >> 6;     // wave 0..7 ; owns units [16w,16w+16)
    const int l = tid & 63;
    const int n = l & 15;       // batch col (B) / row-in-tile (A)
    const int q = l >> 4;       // k-group
    const int b0 = blockIdx.x * BT;
    const float* xrow = x + (size_t)(b0 + n) * TLEN;

    // ---- W_ih1 / W_hh1 fragments in registers (bf16) ----
    s16x8 wi1f[4][4], wh1f[4][4];
    #pragma unroll
    for (int c = 0; c < 4; ++c) {
        #pragma unroll
        for (int tile = 0; tile < 4; ++tile) {
            const int g  = tile * 128 + w * 16 + n;   // gate row
            const int k0 = c * 32 + q * 8;
            const float* p1 = Wih1 + g * HDIM + k0;
            const float* p2 = Whh1 + g * HDIM + k0;
            s16x8 a, b;
            #pragma unroll
            for (int j = 0; j < 8; ++j) { a[j] = (short)f2bf(p1[j]); b[j] = (short)f2bf(p2[j]); }
            wi1f[c][tile] = a; wh1f[c][tile] = b;
        }
    }

    // ---- W_hh0 into LDS, fragment-ordered ----
    for (int s2 = tid; s2 < 8192; s2 += 512) {
        const int ll = s2 & 63, tl = (s2 >> 6) & 3, ww = (s2 >> 8) & 7, cc = s2 >> 11;
        const int g  = tl * 128 + ww * 16 + (ll & 15);
        const int k0 = cc * 32 + (ll >> 4) * 8;
        const float* p = Whh0 + g * HDIM + k0;
        s16x8 a;
        #pragma unroll
        for (int j = 0; j < 8; ++j) a[j] = (short)f2bf(p[j]);
        *(s16x8*)&w0lds[s2 * 8] = a;
    }

    // ---- per-lane constants: packed-bf16 biases + x-weight ----
    const int u0 = w * 16 + q * 4;          // first of this lane's 4 units
    uint32_t b0p[8], b1p[8], wxp[8];
    #pragma unroll
    for (int i = 0; i < 8; ++i) {
        const int tr0 = 2 * i;
        const int tile = tr0 >> 2, r0 = tr0 & 3;
        const int g0 = tile * 128 + u0 + r0;
        const int g1 = g0 + 1;
        b0p[i] = ((uint32_t)f2bf(bih0[g1] + bhh0[g1]) << 16) | f2bf(bih0[g0] + bhh0[g0]);
        b1p[i] = ((uint32_t)f2bf(bih1[g1] + bhh1[g1]) << 16) | f2bf(bih1[g0] + bhh1[g0]);
        wxp[i] = ((uint32_t)f2bf(Wih0[g1]) << 16) | f2bf(Wih0[g0]);
    }

    // zero h1 buffer read at iter(0) (h1[-1] = 0)
    for (int s2 = tid; s2 < 512; s2 += 512) { /* 2048 shorts = 1024 u32; 512 threads x2 */ }
    for (int s2 = tid; s2 < 1024; s2 += 512) ((uint32_t*)h1f1)[s2] = 0u;

    // B-fragment write slot for this lane's 4 units
    const int cp  = u0 >> 5;
    const int kbp = (u0 >> 3) & 3;
    const int j0  = u0 & 7;
    const int fragoff = (cp * 64 + (n + 16 * kbp)) * 8 + j0;   // short index

    float c0v[4] = {0.f, 0.f, 0.f, 0.f};
    float c1v[4] = {0.f, 0.f, 0.f, 0.f};
    float hfin[4];

    // ---- prologue: h0[0] = pointwise(b0 + wx*x[0])  (h0[-1]=0 so no MFMA) ----
    {
        const float x0v = xrow[0];
        s16x4 hw;
        #pragma unroll
        for (int r = 0; r < 4; ++r) {
            const float a_i = fmaf(UNPK(wxp, r),      x0v, UNPK(b0p, r));
            const float a_f = fmaf(UNPK(wxp, 4 + r),  x0v, UNPK(b0p, 4 + r));
            const float a_g = fmaf(UNPK(wxp, 8 + r),  x0v, UNPK(b0p, 8 + r));
            const float a_o = fmaf(UNPK(wxp, 12 + r), x0v, UNPK(b0p, 12 + r));
            const float ig = sigmoidf_(a_i);
            const float fg = sigmoidf_(a_f); (void)fg;
            const float gg = tanhf_(a_g);
            const float og = sigmoidf_(a_o);
            const float cc = ig * gg;          // f*c(-1) = 0
            c0v[r] = cc;
            hw[r] = (short)f2bf(og * tanhf_(cc));
        }
        *(s16x4*)&h0f0[fragoff] = hw;
    }
    __syncthreads();   // w0lds, h0f0, h1f1 ready

// ITER(T): consumes h0[T] (H0R) and h1[T-1] (H1R); produces h1[T] (H1W) and
// h0[T+1] (H0W). MFMA block first (gates1(T) then pre-gates0(T+1)), then both
// pointwise blocks on the VALU, one barrier at the end.
#define ITER(T, H0R, H0W, H1R, H1W) do {                                      \
    const float xnext_ = xrow[(T) + 1];                                       \
    s16x8 hb0_[4], hb1_[4];                                                   \
    _Pragma("unroll")                                                         \
    for (int c = 0; c < 4; ++c) {                                             \
        hb0_[c] = *(const s16x8*)&(H0R)[(c * 64 + l) * 8];                    \
        hb1_[c] = *(const s16x8*)&(H1R)[(c * 64 + l) * 8];                    \
    }                                                                         \
    /* phase3: acc1 = b1 + Wih1@h0[T] + Whh1@h1[T-1] (bias via C operand) */  \
    f32x4 acc1_[4];                                                           \
    _Pragma("unroll")                                                         \
    for (int tile = 0; tile < 4; ++tile) {                                    \
        f32x4 cinit;                                                          \
        _Pragma("unroll")                                                     \
        for (int r = 0; r < 4; ++r) cinit[r] = UNPK(b1p, tile * 4 + r);       \
        acc1_[tile] = __builtin_amdgcn_mfma_f32_16x16x32_bf16(wi1f[0][tile], hb0_[0], cinit, 0, 0, 0); \
    }                                                                         \
    _Pragma("unroll")                                                         \
    for (int c = 1; c < 4; ++c) {                                             \
        _Pragma("unroll")                                                     \
        for (int tile = 0; tile < 4; ++tile)                                  \
            acc1_[tile] = __builtin_amdgcn_mfma_f32_16x16x32_bf16(wi1f[c][tile], hb0_[c], acc1_[tile], 0, 0, 0); \
    }                                                                         \
    _Pragma("unroll")                                                         \
    for (int c = 0; c < 4; ++c) {                                             \
        _Pragma("unroll")                                                     \
        for (int tile = 0; tile < 4; ++tile)                                  \
            acc1_[tile] = __builtin_amdgcn_mfma_f32_16x16x32_bf16(wh1f[c][tile], hb1_[c], acc1_[tile], 0, 0, 0); \
    }                                                                         \
    /* phase1': acc0 = Whh0 @ h0[T]  -> pre-gates for step T+1 */             \
    f32x4 acc0_[4];                                                           \
    _Pragma("unroll")                                                         \
    for (int tile = 0; tile < 4; ++tile) {                                    \
        _Pragma("unroll")                                                     \
        for (int r = 0; r < 4; ++r) acc0_[tile][r] = 0.0f;                    \
    }                                                                         \
    _Pragma("unroll")                                                         \
    for (int c = 0; c < 4; ++c) {                                             \
        _Pragma("unroll")                                                     \
        for (int tile = 0; tile < 4; ++tile) {                                \
            const s16x8 a = *(const s16x8*)&w0lds[(((c * 8 + w) * 4 + tile) * 64 + l) * 8]; \
            acc0_[tile] = __builtin_amdgcn_mfma_f32_16x16x32_bf16(a, hb0_[c], acc0_[tile], 0, 0, 0); \
        }                                                                     \
    }                                                                         \
    /* phase4: layer-1 pointwise -> h1[T] */                                  \
    {                                                                         \
        s16x4 hw;                                                             \
        _Pragma("unroll")                                                     \
        for (int r = 0; r < 4; ++r) {                                         \
            const float ig = sigmoidf_(acc1_[0][r]);                          \
            const float fg = sigmoidf_(acc1_[1][r]);                          \
            const float gg = tanhf_(acc1_[2][r]);                             \
            const float og = sigmoidf_(acc1_[3][r]);                          \
            const float cc = fmaf(fg, c1v[r], ig * gg);                       \
            c1v[r] = cc;                                                      \
            hw[r] = (short)f2bf(og * tanhf_(cc));                             \
        }                                                                     \
        *(s16x4*)&(H1W)[fragoff] = hw;                                        \
    }                                                                         \
    /* phase2': layer-0 pointwise -> h0[T+1] (adds bias + wx*x[T+1]) */       \
    {                                                                         \
        s16x4 hw;                                                             \
        _Pragma("unroll")                                                     \
        for (int tile = 0; tile < 4; ++tile) {                                \
            _Pragma("unroll")                                                 \
            for (int r = 0; r < 4; ++r) {                                     \
                const int tr = tile * 4 + r;                                  \
                acc0_[tile][r] += fmaf(UNPK(wxp, tr), xnext_, UNPK(b0p, tr)); \
            }                                                                 \
        }                                                                     \
        _Pragma("unroll")                                                     \
        for (int r = 0; r < 4; ++r) {                                         \
            const float ig = sigmoidf_(acc0_[0][r]);                          \
            const float fg = sigmoidf_(acc0_[1][r]);                          \
            const float gg = tanhf_(acc0_[2][r]);                             \
            const float og = sigmoidf_(acc0_[3][r]);                          \
            const float cc = fmaf(fg, c0v[r], ig * gg);                       \
            c0v[r] = cc;                                                      \
            hw[r] = (short)f2bf(og * tanhf_(cc));                             \
        }                                                                     \
        *(s16x4*)&(H0W)[fragoff] = hw;                                        \
    }                                                                         \
    __syncthreads();                                                          \
} while (0)

    // loop t = 0..509 in pairs, then t = 510, then epilogue t = 511
    #pragma unroll 1
    for (int t = 0; t < 510; t += 2) {
        ITER(t,     h0f0, h0f1, h1f1, h1f0);   // even
        ITER(t + 1, h0f1, h0f0, h1f0, h1f1);   // odd
    }
    ITER(510, h0f0, h0f1, h1f1, h1f0);         // even; produces h0[511], h1[510]

    // ---- epilogue t=511: gates1 only, h1[511] kept in regs ----
    {
        s16x8 hb0_[4], hb1_[4];
        #pragma unroll
        for (int c = 0; c < 4; ++c) {
            hb0_[c] = *(const s16x8*)&h0f1[(c * 64 + l) * 8];   // h0[511]
            hb1_[c] = *(const s16x8*)&h1f0[(c * 64 + l) * 8];   // h1[510]
        }
        f32x4 acc1_[4];
        #pragma unroll
        for (int tile = 0; tile < 4; ++tile) {
            f32x4 cinit;
            #pragma unroll
            for (int r = 0; r < 4; ++r) cinit[r] = UNPK(b1p, tile * 4 + r);
            acc1_[tile] = __builtin_amdgcn_mfma_f32_16x16x32_bf16(wi1f[0][tile], hb0_[0], cinit, 0, 0, 0);
        }
        #pragma unroll
        for (int c = 1; c < 4; ++c) {
            #pragma unroll
            for (int tile = 0; tile < 4; ++tile)
                acc1_[tile] = __builtin_amdgcn_mfma_f32_16x16x32_bf16(wi1f[c][tile], hb0_[c], acc1_[tile], 0, 0, 0);
        }
        #pragma unroll
        for (int c = 0; c < 4; ++c) {
            #pragma unroll
            for (int tile = 0; tile < 4; ++tile)
                acc1_[tile] = __builtin_amdgcn_mfma_f32_16x16x32_bf16(wh1f[c][tile], hb1_[c], acc1_[tile], 0, 0, 0);
        }
        #pragma unroll
        for (int r = 0; r < 4; ++r) {
            const float ig = sigmoidf_(acc1_[0][r]);
            const float fg = sigmoidf_(acc1_[1][r]);
            const float gg = tanhf_(acc1_[2][r]);
            const float og = sigmoidf_(acc1_[3][r]);
            const float cc = fmaf(fg, c1v[r], ig * gg);
            hfin[r] = og * tanhf_(cc);
        }
    }

    // ---- head: reuse w0lds as f32 scratch ----
    float* headH = (float*)w0lds;            // [16][128]
    float* headL = ((float*)w0lds) + 2048;   // [16][64]
    {
        f32x4 hf;
        #pragma unroll
        for (int r = 0; r < 4; ++r) hf[r] = hfin[r];
        *(f32x4*)&headH[n * HDIM + u0] = hf;
    }
    __syncthreads();

    #pragma unroll
    for (int rep = 0; rep < 2; ++rep) {
        const int idx = tid + rep * 512;     // 1024 = 16 batch * 64 hidden
        const int nn = idx >> 6, j = idx & 63;
        float s = b1[j];
        const float* wrow = W1 + j * HDIM;
        const float* hrow = headH + nn * HDIM;
        #pragma unroll
        for (int k = 0; k < HDIM; k += 4) {
            const f32x4 hv = *(const f32x4*)&hrow[k];
            const f32x4 wv = *(const f32x4*)&wrow[k];
            s += hv[0]*wv[0] + hv[1]*wv[1] + hv[2]*wv[2] + hv[3]*wv[3];
        }
        headL[nn * 64 + j] = fmaxf(s, 0.0f);
    }
    __syncthreads();

    if (tid < 128) {
        const int nn = tid >> 3, cls = tid & 7;
        float s = b2[cls];
        const float* wrow = W2 + cls * 64;
        const float* hrow = headL + nn * 64;
        #pragma unroll
        for (int k = 0; k < 64; k += 4) {
            const f32x4 hv = *(const f32x4*)&hrow[k];
            const f32x4 wv = *(const f32x4*)&wrow[k];
            s += hv[0]*wv[0] + hv[1]*wv[1] + hv[2]*wv[2] + hv[3]*wv[3];
        }
        out[(size_t)(b0 + nn) * 8 + cls] = s;
    }
}

extern "C" void kernel_launch(void* const* d_in, const int* in_sizes, int n_in,
                              void* d_out, int out_size, void* d_ws, size_t ws_size,
                              hipStream_t stream) {
    const float* x    = (const float*)d_in[0];
    const float* Wih0 = (const float*)d_in[1];
    const float* Whh0 = (const float*)d_in[2];
    const float* bih0 = (const float*)d_in[3];
    const float* bhh0 = (const float*)d_in[4];
    const float* Wih1 = (const float*)d_in[5];
    const float* Whh1 = (const float*)d_in[6];
    const float* bih1 = (const float*)d_in[7];
    const float* bhh1 = (const float*)d_in[8];
    const float* W1   = (const float*)d_in[9];
    const float* b1   = (const float*)d_in[10];
    const float* W2   = (const float*)d_in[11];
    const float* b2   = (const float*)d_in[12];
    float* outp = (float*)d_out;

    lstm_fused_kernel<<<128, 512, 0, stream>>>(
        x, Wih0, Whh0, bih0, bhh0, Wih1, Whh1, bih1, bhh1, W1, b1, W2, b2, outp);
}